// Round 5
// baseline (489.835 us; speedup 1.0000x reference)
//
#include <hip/hip_runtime.h>

typedef unsigned short u16;
typedef unsigned int u32;
typedef __bf16 bf16x8 __attribute__((ext_vector_type(8)));
typedef float f32x4 __attribute__((ext_vector_type(4)));

#define BB 2
#define SS 2048
#define HH 2048
#define NHH 16
#define HDD 128

__device__ __forceinline__ float b2f(u16 u) {
  union { u32 i; float f; } v; v.i = ((u32)u) << 16; return v.f;
}
__device__ __forceinline__ u16 f2b(float f) {
  union { float f; u32 i; } v; v.f = f;
  u32 x = v.i;
  u32 r = (x + 0x7fffu + ((x >> 16) & 1u)) >> 16;
  return (u16)r;
}

// async global->LDS 16B: LDS dest = wave-uniform base + lane*16
__device__ __forceinline__ void gload_lds16(const u16* g, u16* l) {
  __builtin_amdgcn_global_load_lds(
      (const __attribute__((address_space(1))) u32*)g,
      (__attribute__((address_space(3))) u32*)l, 16, 0, 0);
}

// Fused f32 -> bf16 conversion for 5 tensors; blockIdx.y selects tensor.
__global__ __launch_bounds__(256) void cvt_kernel(
    const float* __restrict__ s0, u16* __restrict__ d0, int n0,
    const float* __restrict__ s1, u16* __restrict__ d1, int n1,
    const float* __restrict__ s2, u16* __restrict__ d2, int n2,
    const float* __restrict__ s3, u16* __restrict__ d3, int n3,
    const float* __restrict__ s4, u16* __restrict__ d4, int n4)
{
  const float* s; u16* d; int n;
  switch (blockIdx.y) {
    case 0: s = s0; d = d0; n = n0; break;
    case 1: s = s1; d = d1; n = n1; break;
    case 2: s = s2; d = d2; n = n2; break;
    case 3: s = s3; d = d3; n = n3; break;
    default: s = s4; d = d4; n = n4; break;
  }
  int nq = n >> 2;
  for (int q = blockIdx.x * 256 + threadIdx.x; q < nq; q += gridDim.x * 256) {
    float4 v = *(const float4*)(s + (size_t)q * 4);
    ushort4 o;
    o.x = f2b(v.x); o.y = f2b(v.y); o.z = f2b(v.z); o.w = f2b(v.w);
    *(ushort4*)(d + (size_t)q * 4) = o;
  }
}

// Transpose-convert Wv (rows 4096..6143 of f32 Wqkv) -> bf16 WvT[n][k] = Wv[k][n]
__global__ __launch_bounds__(256) void transpose_wv_kernel(
    const float* __restrict__ Wqkv, u16* __restrict__ WvT)
{
  __shared__ float tile[64][65];
  const int t = threadIdx.x;
  const int r0 = blockIdx.y * 64;   // Wv row block (k-index of WvT)
  const int c0 = blockIdx.x * 64;   // Wv col block (n-index of WvT)
  const int tr = t >> 4;            // 0..15
  const int tc = (t & 15) * 4;      // 0,4,..,60
#pragma unroll
  for (int i = 0; i < 4; ++i) {
    int r = tr + i * 16;
    float4 v = *(const float4*)(Wqkv + (size_t)(4096 + r0 + r) * 2048 + c0 + tc);
    tile[r][tc] = v.x; tile[r][tc + 1] = v.y; tile[r][tc + 2] = v.z; tile[r][tc + 3] = v.w;
  }
  __syncthreads();
#pragma unroll
  for (int i = 0; i < 4; ++i) {
    int n = tr + i * 16;            // col of Wv = output row
    ushort4 o;
    o.x = f2b(tile[tc + 0][n]);
    o.y = f2b(tile[tc + 1][n]);
    o.z = f2b(tile[tc + 2][n]);
    o.w = f2b(tile[tc + 3][n]);
    *(ushort4*)(WvT + (size_t)(c0 + n) * 2048 + r0 + tc) = o;
  }
}

// bc2[row] = bc[row] + dot(Wc[row,:], bv)   (320 rows; 80 blocks x 4 waves)
__global__ __launch_bounds__(256) void bc2_kernel(
    const u16* __restrict__ Wcb, const float* __restrict__ bqkv,
    const float* __restrict__ bc, float* __restrict__ bc2)
{
  const int t = threadIdx.x;
  const int lane = t & 63, w = t >> 6;
  const int row = blockIdx.x * 4 + w;
  const float* bv = bqkv + 4096;
  float s = 0.f;
  for (int j = lane; j < 2048; j += 64)
    s += b2f(Wcb[(size_t)row * 2048 + j]) * bv[j];
#pragma unroll
  for (int o = 32; o; o >>= 1) s += __shfl_xor(s, o, 64);
  if (lane == 0) bc2[row] = bc[row] + s;
}

// ---------------------------------------------------------------------------
// 256x256 8-phase GEMM (T1..T5 stack, m201 template) for the QK projection.
// N=4096 now (V folded into Wvc) -> grid 16x16 = 256 blocks = ONE exact
// dispatch round at 1 block/CU (was 384 = 1.5 rounds, 75% packing ceiling).
// ---------------------------------------------------------------------------

template<int ISA>
__device__ __forceinline__ void stage_half(
    const u16* __restrict__ src, u16* ldsmat, int h,
    int tb, int kb, int ld, int wid, int lane)
{
#pragma unroll
  for (int l = 0; l < 2; ++l) {
    const int i = wid * 2 + l;
    const int rp = i * 8 + (lane >> 3);      // storage row within half, 0..127
    int r;
    if (ISA) r = (rp & 63) + ((rp >> 6) << 7) + h * 64;
    else     r = ((rp >> 5) << 6) + h * 32 + (rp & 31);
    const int c = (lane & 7) ^ (lane >> 3);  // inverse-swizzled global chunk
    gload_lds16(src + (size_t)(tb + r) * ld + kb + c * 8,
                ldsmat + (size_t)(h * 128 + i * 8) * 64);
  }
}

#define BAR()   __builtin_amdgcn_s_barrier()
#define PRIO1() __builtin_amdgcn_s_setprio(1)
#define PRIO0() __builtin_amdgcn_s_setprio(0)

#define LDA_READ(BP, MH) do {                                                  \
  const u16* _p = (BP);                                                        \
  _Pragma("unroll") for (int mi = 0; mi < 4; ++mi) {                           \
    const int _rho = (MH) * 128 + wr * 64 + mi * 16 + lm;                      \
    _Pragma("unroll") for (int ks = 0; ks < 2; ++ks)                           \
      af[mi][ks] = *(const bf16x8*)&_p[(size_t)_rho * 64 +                     \
                                       ((((ks << 2) + quad) ^ (lm & 7)) << 3)];\
  }                                                                            \
} while (0)

#define LDB_READ(BP, NH) do {                                                  \
  const u16* _p = (BP);                                                        \
  _Pragma("unroll") for (int ni = 0; ni < 2; ++ni) {                           \
    const int _rho = (NH) * 128 + wc * 32 + ni * 16 + lm;                      \
    _Pragma("unroll") for (int ks = 0; ks < 2; ++ks)                           \
      bfr[NH][ni][ks] = *(const bf16x8*)&_p[(size_t)_rho * 64 +                \
                                       ((((ks << 2) + quad) ^ (lm & 7)) << 3)];\
  }                                                                            \
} while (0)

#define MFMA_Q(MH, NH) do {                                                    \
  _Pragma("unroll") for (int mi = 0; mi < 4; ++mi)                             \
    _Pragma("unroll") for (int ni = 0; ni < 2; ++ni)                           \
      _Pragma("unroll") for (int ks = 0; ks < 2; ++ks)                         \
        acc[(MH) * 4 + mi][(NH) * 2 + ni] =                                    \
            __builtin_amdgcn_mfma_f32_16x16x32_bf16(                           \
                af[mi][ks], bfr[NH][ni][ks],                                   \
                acc[(MH) * 4 + mi][(NH) * 2 + ni], 0, 0, 0);                   \
} while (0)

__global__ __launch_bounds__(512, 2) void gemm256_rope_kernel(
    const u16* __restrict__ A, const u16* __restrict__ Bw,
    const float* __restrict__ bias, u16* __restrict__ C,
    int M, int N, int K, int lda, int ldb, int ldc)
{
  __shared__ u16 lds[2][2][256 * 64];   // [buf][A/B][storage] = 128 KB
  const int t = threadIdx.x;
  const int lane = t & 63, wid = t >> 6;
  const int wr = wid >> 2, wc = wid & 3;         // 2M x 4N wave grid
  const int quad = lane >> 4, lm = lane & 15;

  // T1: bijective XCD-chunked swizzle (nwg % 8 == 0), bx-major decode.
  const int nwg = gridDim.x * gridDim.y;
  const int lid = blockIdx.y * gridDim.x + blockIdx.x;
  const int sb = (lid & 7) * (nwg >> 3) + (lid >> 3);
  const int m0 = (sb % gridDim.y) * 256, n0 = (sb / gridDim.y) * 256;

  u16* As0 = &lds[0][0][0]; u16* Bs0 = &lds[0][1][0];
  u16* As1 = &lds[1][0][0]; u16* Bs1 = &lds[1][1][0];

  f32x4 acc[8][4] = {};
  bf16x8 af[4][2];         // current A quadrant [mi][ks]
  bf16x8 bfr[2][2][2];     // [nh][ni][ks], both halves live

  const int NT = K >> 6;   // K-tiles of 64

  // prologue: K-tile0 {A0,B0,B1,A1}, K-tile1 {A0,B0,B1}; K-tile1.A1 at ph1.
  stage_half<1>(A,  As0, 0, m0, 0, lda, wid, lane);
  stage_half<0>(Bw, Bs0, 0, n0, 0, ldb, wid, lane);
  stage_half<0>(Bw, Bs0, 1, n0, 0, ldb, wid, lane);
  stage_half<1>(A,  As0, 1, m0, 0, lda, wid, lane);
  asm volatile("s_waitcnt vmcnt(4)" ::: "memory");
  stage_half<1>(A,  As1, 0, m0, 64, lda, wid, lane);
  stage_half<0>(Bw, Bs1, 0, n0, 64, ldb, wid, lane);
  stage_half<0>(Bw, Bs1, 1, n0, 64, ldb, wid, lane);
  asm volatile("s_waitcnt vmcnt(6)" ::: "memory");
  BAR();

  for (int it2 = 0; it2 < (NT >> 1); ++it2) {
    int kb1 = (it2 * 2 + 1) << 6;                       // always < K
    int kb2 = (it2 * 2 + 2) << 6; if (kb2 >= K) kb2 -= K;  // wrap: safe garbage
    int kb3 = (it2 * 2 + 3) << 6; if (kb3 >= K) kb3 -= K;

    // ph1: read A0,B0 (buf0); stage (2t+1).A1 -> As1
    LDA_READ(As0, 0); LDB_READ(Bs0, 0);
    stage_half<1>(A, As1, 1, m0, kb1, lda, wid, lane);
    BAR(); PRIO1(); MFMA_Q(0, 0); PRIO0(); BAR();
    // ph2: read B1 (buf0); stage (2t+2).A0 -> As0
    LDB_READ(Bs0, 1);
    stage_half<1>(A, As0, 0, m0, kb2, lda, wid, lane);
    BAR(); PRIO1(); MFMA_Q(0, 1); PRIO0(); BAR();
    // ph3: read A1 (buf0); stage (2t+2).B0 -> Bs0
    LDA_READ(As0, 1);
    stage_half<0>(Bw, Bs0, 0, n0, kb2, ldb, wid, lane);
    BAR(); PRIO1(); MFMA_Q(1, 1); PRIO0(); BAR();
    // ph4: stage (2t+2).B1 -> Bs0; counted wait: K-tile 2t+1 fully landed
    stage_half<0>(Bw, Bs0, 1, n0, kb2, ldb, wid, lane);
    asm volatile("s_waitcnt vmcnt(6)" ::: "memory");
    BAR(); PRIO1(); MFMA_Q(1, 0); PRIO0(); BAR();
    // ph5: read A0,B0 (buf1); stage (2t+2).A1 -> As0
    LDA_READ(As1, 0); LDB_READ(Bs1, 0);
    stage_half<1>(A, As0, 1, m0, kb2, lda, wid, lane);
    BAR(); PRIO1(); MFMA_Q(0, 0); PRIO0(); BAR();
    // ph6: read B1 (buf1); stage (2t+3).A0 -> As1
    LDB_READ(Bs1, 1);
    stage_half<1>(A, As1, 0, m0, kb3, lda, wid, lane);
    BAR(); PRIO1(); MFMA_Q(0, 1); PRIO0(); BAR();
    // ph7: read A1 (buf1); stage (2t+3).B0 -> Bs1
    LDA_READ(As1, 1);
    stage_half<0>(Bw, Bs1, 0, n0, kb3, ldb, wid, lane);
    BAR(); PRIO1(); MFMA_Q(1, 1); PRIO0(); BAR();
    // ph8: stage (2t+3).B1 -> Bs1; counted wait: K-tile 2t+2 fully landed
    stage_half<0>(Bw, Bs1, 1, n0, kb3, ldb, wid, lane);
    asm volatile("s_waitcnt vmcnt(6)" ::: "memory");
    BAR(); PRIO1(); MFMA_Q(1, 0); PRIO0(); BAR();
  }
  // drain in-flight LDS DMA before waves exit (LDS dealloc hazard)
  asm volatile("s_waitcnt vmcnt(0)" ::: "memory");

  // epilogue: bias (+RoPE on head-cols 0..31 for Q,K) -> bf16 store
  const int cbase = n0 + wc * 64;
  const float ropefreq = exp2f(-(float)lm * 0.8304820237218406f);
  const bool do_rope = ((wc & 1) == 0) && (cbase < 4096);
  float b0 = 0.f, b1 = 0.f;
  if (do_rope) { b0 = bias[cbase + lm]; b1 = bias[cbase + lm + 16]; }

#pragma unroll
  for (int mi8 = 0; mi8 < 8; ++mi8) {
    const int gm = m0 + wr * 128 + mi8 * 16 + quad * 4;
    int jstart = 0;
    if (do_rope) {
      jstart = 2;
      const int gn0 = cbase + lm, gn1 = gn0 + 16;
#pragma unroll
      for (int rg = 0; rg < 4; ++rg) {
        int rs = gm + rg;
        float sn, cs;
        __sincosf((float)(rs & (SS - 1)) * ropefreq, &sn, &cs);
        float x0 = acc[mi8][0][rg] + b0, x1 = acc[mi8][1][rg] + b1;
        C[(size_t)rs * ldc + gn0] = f2b(x0 * cs - x1 * sn);
        C[(size_t)rs * ldc + gn1] = f2b(x1 * cs + x0 * sn);
      }
    }
#pragma unroll
    for (int nj = 0; nj < 4; ++nj) {
      if (nj < jstart) continue;
      const int gn = cbase + nj * 16 + lm;
      if (gn < N) {
        f32x4 a = acc[mi8][nj];
        float bs = bias[gn];
#pragma unroll
        for (int rg = 0; rg < 4; ++rg)
          C[(size_t)(gm + rg) * ldc + gn] = f2b(a[rg] + bs);
      }
    }
  }
}

// C = A[M,K](bf16) @ Bw[N,K](bf16)^T + bias(f32). OUT_F32 ? f32 : bf16 store.
// BIAS_ROW: bias indexed by output row. NOBIAS: no bias add (weight-fold GEMM).
// blockIdx.z batching via strideB/strideC (elements).
template<int OUT_F32, int ROPE, int BIAS_ROW, int NOBIAS>
__global__ __launch_bounds__(256) void gemm_bias_kernel(
    const u16* __restrict__ A, const u16* __restrict__ Bw,
    const float* __restrict__ bias, void* __restrict__ Cv,
    int M, int N, int K, int lda, int ldb, int ldc,
    size_t strideB, size_t strideC)
{
  __shared__ u16 Asf[128 * 4 * 8];   // [row][chunk][8]  8KB
  __shared__ u16 Bsf[128 * 4 * 8];
  const int t = threadIdx.x;
  const int m0 = blockIdx.y * 128;
  const int n0 = blockIdx.x * 128;
  const int lane = t & 63, wid = t >> 6;
  const int wm = (wid >> 1) * 64, wn = (wid & 1) * 64;
  const int quad = lane >> 4, lm = lane & 15;

  const u16* Bz = Bw + (size_t)blockIdx.z * strideB;

  // staging lane decomposition: lane = r16*4 + c  (16 rows x 4 chunks per gload)
  const int r16 = lane >> 2;
  const int swz = ((lane >> 2) & 3) ^ ((lane >> 4) & 3);
  const int kc = ((lane & 3) ^ swz) * 8;     // swizzled k-chunk (element offset)
  const int fswz = (lm & 3) ^ ((lm >> 2) & 3);

  f32x4 acc[4][4] = {};

  for (int k0 = 0; k0 < K; k0 += 32) {
    __syncthreads();
#pragma unroll
    for (int it = 0; it < 2; ++it) {
      int g = wid * 2 + it;                  // 16-row group 0..7
      int r = g * 16 + r16;
      gload_lds16(A + (size_t)(m0 + r) * lda + k0 + kc, &Asf[(size_t)g * 512]);
      gload_lds16(Bz + (size_t)(n0 + r) * ldb + k0 + kc, &Bsf[(size_t)g * 512]);
    }
    __syncthreads();
    bf16x8 af[4], bf[4];
#pragma unroll
    for (int i = 0; i < 4; ++i) {
      int row = wm + i * 16 + lm;
      af[i] = *(const bf16x8*)&Asf[(size_t)(row * 4 + (quad ^ fswz)) * 8];
    }
#pragma unroll
    for (int j = 0; j < 4; ++j) {
      int row = wn + j * 16 + lm;
      bf[j] = *(const bf16x8*)&Bsf[(size_t)(row * 4 + (quad ^ fswz)) * 8];
    }
#pragma unroll
    for (int i = 0; i < 4; ++i)
#pragma unroll
      for (int j = 0; j < 4; ++j)
        acc[i][j] = __builtin_amdgcn_mfma_f32_16x16x32_bf16(af[i], bf[j], acc[i][j], 0, 0, 0);
  }

  float* Cf = (float*)Cv + (OUT_F32 ? (size_t)blockIdx.z * strideC : 0);
  u16* Cu = (u16*)Cv + (OUT_F32 ? 0 : (size_t)blockIdx.z * strideC);
  const float ropefreq = ROPE ? exp2f(-(float)lm * 0.8304820237218406f) : 0.f;
  const bool do_rope = ROPE && (wn == 0) && (n0 < 4096);

#pragma unroll
  for (int i = 0; i < 4; ++i) {
    int gm = m0 + wm + i * 16 + quad * 4;
    int jstart = 0;
    if (do_rope) {
      jstart = 2;
      int gn0 = n0 + lm, gn1 = gn0 + 16;
      float b0 = bias[gn0], b1 = bias[gn1];
#pragma unroll
      for (int rg = 0; rg < 4; ++rg) {
        int rs = gm + rg;
        float sn, cs;
        __sincosf((float)(rs & (SS - 1)) * ropefreq, &sn, &cs);
        float x0 = acc[i][0][rg] + b0, x1 = acc[i][1][rg] + b1;
        Cu[(size_t)rs * ldc + gn0] = f2b(x0 * cs - x1 * sn);
        Cu[(size_t)rs * ldc + gn1] = f2b(x1 * cs + x0 * sn);
      }
    }
#pragma unroll
    for (int j = 0; j < 4; ++j) {
      if (j < jstart) continue;
      int gn = n0 + wn + j * 16 + lm;
      if (gn < N) {
        f32x4 a = acc[i][j];
#pragma unroll
        for (int rg = 0; rg < 4; ++rg) {
          float bsv = NOBIAS ? 0.f : (BIAS_ROW ? bias[gm + rg] : bias[gn]);
          if (OUT_F32) Cf[(size_t)(gm + rg) * ldc + gn] = a[rg] + bsv;
          else         Cu[(size_t)(gm + rg) * ldc + gn] = f2b(a[rg] + bsv);
        }
      }
    }
  }
}

// MFMA causal flash attention, S^T formulation. Block = 4 waves.
// 512 blocks; each block processes the q-tile PAIR (31-pr, pr) -> uniform
// 33 k-tiles/block (no causal tail). Inline global->LDS staging (register
// prefetch spilled in round 3; reverted).
__global__ __launch_bounds__(256) void attn_mfma_kernel(
    const u16* __restrict__ qkv, const u16* __restrict__ vrt, u16* __restrict__ out)
{
  __shared__ u16 Kt[64 * 16 * 8];  // chunk(kp,dq) at kp*16 + (dq^(kp&15))   16KB
  __shared__ u16 Vt[8][128][8];    // [kq][d][j] = V[kb+kq*8+j][d]           16KB
  __shared__ u16 Pa[4][16 * 64];   // [w][q*64 + unit-swizzled]               8KB

  const int t = threadIdx.x;
  const int lane = t & 63, w = t >> 6;
  const int quad = lane >> 4, lm = lane & 15;
  const int lid = blockIdx.x;          // 0..511
  const int sbx = (lid & 7) * 64 + (lid >> 3);   // XCD-chunked, bijective
  const int bh = sbx >> 4;             // 4 heads per XCD chunk
  const int pr = sbx & 15;             // pair index: q-tiles {31-pr, pr}
  const int b = bh >> 4, h = bh & 15;

  const float scale = 0.08838834764831845f;  // 1/sqrt(128)
  const u16* kbase = qkv + (size_t)b * SS * 6144 + 2048 + h * 128;
  const u16* vbase = vrt + (size_t)bh * 128 * 2048;
  u16* pw = &Pa[w][0];

#pragma unroll 1
  for (int ps = 0; ps < 2; ++ps) {
    const int qt = ps ? pr : (31 - pr);
    const int qw = qt * 64 + w * 16;
    const int nkt = qt + 1;

    // Q fragments (B-operand): Q[qw+lm][dc*32+quad*8+j]
    bf16x8 qf[4];
    {
      const u16* qsrc = qkv + (size_t)(b * SS + qw + lm) * 6144 + h * 128 + quad * 8;
#pragma unroll
      for (int dc = 0; dc < 4; ++dc) qf[dc] = *(const bf16x8*)(qsrc + dc * 32);
    }

    f32x4 Oa[8] = {};                 // [dt]: O[q=quad*4+r][d=dt*16+lm]
    float m_i = -1e30f, l_i = 0.f;    // per-lane softmax state for q = qw+lm

#pragma unroll 1
    for (int kt = 0; kt < nkt; ++kt) {
      const int kb = kt * 64;
      __syncthreads();
#pragma unroll
      for (int it = 0; it < 4; ++it) {
        int c = t + it * 256;
        int kp = c >> 4, dq = c & 15;
        *(uint4*)&Kt[(size_t)(kp * 16 + (dq ^ (kp & 15))) * 8] =
            *(const uint4*)(kbase + (size_t)(kb + kp) * 6144 + dq * 8);
        int d = c >> 3, kq = c & 7;
        *(uint4*)&Vt[kq][d][0] =
            *(const uint4*)(vbase + (size_t)d * 2048 + kb + kq * 8);
      }
      __syncthreads();

      // S^T = K Q^T : C-layout col = q (lane&15), row = kpos_local = quad*4+r
      f32x4 sa[4] = {};
#pragma unroll
      for (int ct = 0; ct < 4; ++ct) {
#pragma unroll
        for (int dc = 0; dc < 4; ++dc) {
          bf16x8 kf = *(const bf16x8*)&Kt[(size_t)((ct * 16 + lm) * 16 +
                                                   ((dc * 4 + quad) ^ lm)) * 8];
          sa[ct] = __builtin_amdgcn_mfma_f32_16x16x32_bf16(kf, qf[dc], sa[ct], 0, 0, 0);
        }
      }
#pragma unroll
      for (int ct = 0; ct < 4; ++ct)
#pragma unroll
        for (int r = 0; r < 4; ++r) sa[ct][r] *= scale;

      if (kt == nkt - 1) {  // diagonal tile: mask kpos > q
        int qpos = qw + lm;
#pragma unroll
        for (int ct = 0; ct < 4; ++ct) {
#pragma unroll
          for (int r = 0; r < 4; ++r)
            if (kb + ct * 16 + quad * 4 + r > qpos) sa[ct][r] = -1e30f;
        }
      }

      // online softmax, per-lane row q = qw+lm
      float mx = sa[0][0];
#pragma unroll
      for (int ct = 0; ct < 4; ++ct)
#pragma unroll
        for (int r = 0; r < 4; ++r) mx = fmaxf(mx, sa[ct][r]);
      mx = fmaxf(mx, __shfl_xor(mx, 16, 64));
      mx = fmaxf(mx, __shfl_xor(mx, 32, 64));
      float mnew = fmaxf(m_i, mx);
      float alpha = __expf(m_i - mnew);
      float ssum = 0.f;
#pragma unroll
      for (int ct = 0; ct < 4; ++ct)
#pragma unroll
        for (int r = 0; r < 4; ++r) {
          float p = __expf(sa[ct][r] - mnew);
          sa[ct][r] = p;
          ssum += p;
        }
      ssum += __shfl_xor(ssum, 16, 64);
      ssum += __shfl_xor(ssum, 32, 64);
      l_i = l_i * alpha + ssum;
      m_i = mnew;

      // redistribute alpha to O rows (q = quad*4+r held at lane lm' = quad*4+r)
      float ar[4];
#pragma unroll
      for (int r = 0; r < 4; ++r) ar[r] = __shfl(alpha, quad * 4 + r, 64);
#pragma unroll
      for (int dt = 0; dt < 8; ++dt)
#pragma unroll
        for (int r = 0; r < 4; ++r) Oa[dt][r] *= ar[r];

      // P^T (C-layout) -> Pa A-frag layout
#pragma unroll
      for (int ct = 0; ct < 4; ++ct) {
        uint2 pk;
        pk.x = (u32)f2b(sa[ct][0]) | ((u32)f2b(sa[ct][1]) << 16);
        pk.y = (u32)f2b(sa[ct][2]) | ((u32)f2b(sa[ct][3]) << 16);
        int u = ct * 2 + (quad >> 1);
        *(uint2*)(pw + lm * 64 + ((u ^ (lm & 7)) * 8) + (quad & 1) * 4) = pk;
      }
      bf16x8 pf0 = *(const bf16x8*)(pw + lm * 64 + ((quad ^ (lm & 7)) * 8));
      bf16x8 pf1 = *(const bf16x8*)(pw + lm * 64 + (((4 + quad) ^ (lm & 7)) * 8));

      // O += P V
#pragma unroll
      for (int dt = 0; dt < 8; ++dt) {
        bf16x8 vf0 = *(const bf16x8*)&Vt[quad][dt * 16 + lm][0];
        bf16x8 vf1 = *(const bf16x8*)&Vt[4 + quad][dt * 16 + lm][0];
        Oa[dt] = __builtin_amdgcn_mfma_f32_16x16x32_bf16(pf0, vf0, Oa[dt], 0, 0, 0);
        Oa[dt] = __builtin_amdgcn_mfma_f32_16x16x32_bf16(pf1, vf1, Oa[dt], 0, 0, 0);
      }
    }

    float inv = 1.0f / l_i;
    float ir[4];
#pragma unroll
    for (int r = 0; r < 4; ++r) ir[r] = __shfl(inv, quad * 4 + r, 64);
    u16* dst = out + (size_t)(b * SS + qw + quad * 4) * 2048 + h * 128 + lm;
#pragma unroll
    for (int r = 0; r < 4; ++r)
#pragma unroll
      for (int dt = 0; dt < 8; ++dt)
        dst[(size_t)r * 2048 + dt * 16] = f2b(Oa[dt][r] * ir[r]);
  }
}

extern "C" void kernel_launch(void* const* d_in, const int* in_sizes, int n_in,
                              void* d_out, int out_size, void* d_ws, size_t ws_size,
                              hipStream_t stream)
{
  (void)in_sizes; (void)n_in; (void)out_size; (void)ws_size;
  const float* X    = (const float*)d_in[0];
  const float* Wqkv = (const float*)d_in[1];
  const float* bqkv = (const float*)d_in[2];
  const float* Wc   = (const float*)d_in[3];
  const float* bc   = (const float*)d_in[4];
  const float* Wr   = (const float*)d_in[5];
  const float* br   = (const float*)d_in[6];
  const float* Wd   = (const float*)d_in[7];
  const float* bd   = (const float*)d_in[8];
  float* out = (float*)d_out;

  char* ws = (char*)d_ws;
  u16* QKV   = (u16*)(ws);                  // 48 MB  [1-5] (V third unused)
  u16* Xb    = (u16*)(ws + 50331648);       // 16 MB  [cvt-..]
  u16* AO    = (u16*)(ws + 50331648);       //        [attn-5]
  u16* Wqkvb = (u16*)(ws + 67108864);       // 24 MB  [cvt-1]
  u16* VrT   = (u16*)(ws + 67108864);       // 16 MB  [3-4] (aliases Wqkvb)
  u16* Wcb   = (u16*)(ws + 92274688);       // 1.25 MB
  u16* Wrb   = (u16*)(ws + 93585408);       // 1.25 MB
  u16* Cb    = (u16*)(ws + 94896128);       // 2.5 MB
  u16* Wdb   = (u16*)(ws + 97517568);       // 8 MB
  u16* WvTb  = (u16*)(ws + 105906176);      // 8 MB   Wv^T bf16
  u16* Wvc   = (u16*)(ws + 114294784);      // 1.5 MB (384x2048, rows 320+ junk)
  float* bc2 = (float*)(ws + 115867648);    // 1.25 KB

  dim3 blk(256);

  // 0. convert f32 inputs -> bf16
  cvt_kernel<<<dim3(512, 5), blk, 0, stream>>>(
      X, Xb, 4096 * 2048,
      Wqkv, Wqkvb, 6144 * 2048,
      Wc, Wcb, 320 * 2048,
      Wr, Wrb, 2048 * 320,
      Wd, Wdb, 2048 * 2048);

  // 0b. WvT = Wv^T (bf16), from f32 Wqkv rows 4096..6143
  transpose_wv_kernel<<<dim3(32, 32), blk, 0, stream>>>(Wqkv, WvTb);
  // 0c. bc2 = bc + Wc @ bv
  bc2_kernel<<<dim3(80), blk, 0, stream>>>(Wcb, bqkv, bc, bc2);
  // 0d. Wvc = Wc @ Wv  (= Wc @ WvT^T), no bias. Rows 320..383 of A are junk
  //     reads into Wrb (in-bounds); output rows 320..383 junk, never used.
  gemm_bias_kernel<0, 0, 0, 1><<<dim3(16, 3), blk, 0, stream>>>(
      Wcb, WvTb, bc, Wvc, 320, 2048, 2048, 2048, 2048, 2048, 0, 0);

  // 1. QK projection with fused RoPE — N=4096, 256 blocks = one exact round
  gemm256_rope_kernel<<<dim3(16, 16), dim3(512), 0, stream>>>(
      Xb, Wqkvb, bqkv, QKV, 4096, 4096, 2048, 2048, 2048, 6144);
  // 2. Cb = X @ Wvc^T + bc2   (V projection folded: == V_hidden @ Wc^T + bc)
  gemm_bias_kernel<0, 0, 0, 0><<<dim3(3, 32), blk, 0, stream>>>(
      Xb, Wvc, bc2, Cb, 4096, 320, 2048, 2048, 2048, 320, 0, 0);
  // 3. VrT = (Cb @ Wr^T)^T + br  == Wr @ Cb^T, per batch (z=2)
  gemm_bias_kernel<0, 0, 1, 0><<<dim3(16, 16, 2), blk, 0, stream>>>(
      Wrb, Cb, br, VrT, 2048, 2048, 320, 320, 320, 2048,
      (size_t)2048 * 320, (size_t)4194304);
  // 4. MFMA causal flash attention -> AO (bf16, hidden layout), paired q-tiles
  attn_mfma_kernel<<<dim3(512), blk, 0, stream>>>(QKV, VrT, AO);
  // 5. output projection -> f32 d_out
  gemm_bias_kernel<1, 0, 0, 0><<<dim3(16, 32), blk, 0, stream>>>(
      AO, Wdb, bd, out, 4096, 2048, 2048, 2048, 2048, 2048, 0, 0);
}

// Round 6
// 469.622 us; speedup vs baseline: 1.0430x; 1.0430x over previous
//
#include <hip/hip_runtime.h>

typedef unsigned short u16;
typedef unsigned int u32;
typedef __bf16 bf16x8 __attribute__((ext_vector_type(8)));
typedef float f32x4 __attribute__((ext_vector_type(4)));

#define BB 2
#define SS 2048
#define HH 2048
#define NHH 16
#define HDD 128

__device__ __forceinline__ float b2f(u16 u) {
  union { u32 i; float f; } v; v.i = ((u32)u) << 16; return v.f;
}
__device__ __forceinline__ u16 f2b(float f) {
  union { float f; u32 i; } v; v.f = f;
  u32 x = v.i;
  u32 r = (x + 0x7fffu + ((x >> 16) & 1u)) >> 16;
  return (u16)r;
}

// async global->LDS 16B: LDS dest = wave-uniform base + lane*16
__device__ __forceinline__ void gload_lds16(const u16* g, u16* l) {
  __builtin_amdgcn_global_load_lds(
      (const __attribute__((address_space(1))) u32*)g,
      (__attribute__((address_space(3))) u32*)l, 16, 0, 0);
}

// Fused f32 -> bf16 conversion for 5 tensors; blockIdx.y selects tensor.
__global__ __launch_bounds__(256) void cvt_kernel(
    const float* __restrict__ s0, u16* __restrict__ d0, int n0,
    const float* __restrict__ s1, u16* __restrict__ d1, int n1,
    const float* __restrict__ s2, u16* __restrict__ d2, int n2,
    const float* __restrict__ s3, u16* __restrict__ d3, int n3,
    const float* __restrict__ s4, u16* __restrict__ d4, int n4)
{
  const float* s; u16* d; int n;
  switch (blockIdx.y) {
    case 0: s = s0; d = d0; n = n0; break;
    case 1: s = s1; d = d1; n = n1; break;
    case 2: s = s2; d = d2; n = n2; break;
    case 3: s = s3; d = d3; n = n3; break;
    default: s = s4; d = d4; n = n4; break;
  }
  int nq = n >> 2;
  for (int q = blockIdx.x * 256 + threadIdx.x; q < nq; q += gridDim.x * 256) {
    float4 v = *(const float4*)(s + (size_t)q * 4);
    ushort4 o;
    o.x = f2b(v.x); o.y = f2b(v.y); o.z = f2b(v.z); o.w = f2b(v.w);
    *(ushort4*)(d + (size_t)q * 4) = o;
  }
}

// Transpose-convert Wv (rows 4096..6143 of f32 Wqkv) -> bf16 WvT[n][k] = Wv[k][n]
__global__ __launch_bounds__(256) void transpose_wv_kernel(
    const float* __restrict__ Wqkv, u16* __restrict__ WvT)
{
  __shared__ float tile[64][65];
  const int t = threadIdx.x;
  const int r0 = blockIdx.y * 64;   // Wv row block (k-index of WvT)
  const int c0 = blockIdx.x * 64;   // Wv col block (n-index of WvT)
  const int tr = t >> 4;            // 0..15
  const int tc = (t & 15) * 4;      // 0,4,..,60
#pragma unroll
  for (int i = 0; i < 4; ++i) {
    int r = tr + i * 16;
    float4 v = *(const float4*)(Wqkv + (size_t)(4096 + r0 + r) * 2048 + c0 + tc);
    tile[r][tc] = v.x; tile[r][tc + 1] = v.y; tile[r][tc + 2] = v.z; tile[r][tc + 3] = v.w;
  }
  __syncthreads();
#pragma unroll
  for (int i = 0; i < 4; ++i) {
    int n = tr + i * 16;            // col of Wv = output row
    ushort4 o;
    o.x = f2b(tile[tc + 0][n]);
    o.y = f2b(tile[tc + 1][n]);
    o.z = f2b(tile[tc + 2][n]);
    o.w = f2b(tile[tc + 3][n]);
    *(ushort4*)(WvT + (size_t)(c0 + n) * 2048 + r0 + tc) = o;
  }
}

// bc2[row] = bc[row] + dot(Wc[row,:], bv)   (320 rows; 80 blocks x 4 waves)
__global__ __launch_bounds__(256) void bc2_kernel(
    const u16* __restrict__ Wcb, const float* __restrict__ bqkv,
    const float* __restrict__ bc, float* __restrict__ bc2)
{
  const int t = threadIdx.x;
  const int lane = t & 63, w = t >> 6;
  const int row = blockIdx.x * 4 + w;
  const float* bv = bqkv + 4096;
  float s = 0.f;
  for (int j = lane; j < 2048; j += 64)
    s += b2f(Wcb[(size_t)row * 2048 + j]) * bv[j];
#pragma unroll
  for (int o = 32; o; o >>= 1) s += __shfl_xor(s, o, 64);
  if (lane == 0) bc2[row] = bc[row] + s;
}

// ---------------------------------------------------------------------------
// 256x256 8-phase GEMM (T1..T5 stack, m201 template) for the QK projection.
// N=4096 (V folded into Wvc) -> grid 16x16 = 256 blocks = one exact round.
// ---------------------------------------------------------------------------

template<int ISA>
__device__ __forceinline__ void stage_half(
    const u16* __restrict__ src, u16* ldsmat, int h,
    int tb, int kb, int ld, int wid, int lane)
{
#pragma unroll
  for (int l = 0; l < 2; ++l) {
    const int i = wid * 2 + l;
    const int rp = i * 8 + (lane >> 3);      // storage row within half, 0..127
    int r;
    if (ISA) r = (rp & 63) + ((rp >> 6) << 7) + h * 64;
    else     r = ((rp >> 5) << 6) + h * 32 + (rp & 31);
    const int c = (lane & 7) ^ (lane >> 3);  // inverse-swizzled global chunk
    gload_lds16(src + (size_t)(tb + r) * ld + kb + c * 8,
                ldsmat + (size_t)(h * 128 + i * 8) * 64);
  }
}

#define BAR()   __builtin_amdgcn_s_barrier()
#define PRIO1() __builtin_amdgcn_s_setprio(1)
#define PRIO0() __builtin_amdgcn_s_setprio(0)

#define LDA_READ(BP, MH) do {                                                  \
  const u16* _p = (BP);                                                        \
  _Pragma("unroll") for (int mi = 0; mi < 4; ++mi) {                           \
    const int _rho = (MH) * 128 + wr * 64 + mi * 16 + lm;                      \
    _Pragma("unroll") for (int ks = 0; ks < 2; ++ks)                           \
      af[mi][ks] = *(const bf16x8*)&_p[(size_t)_rho * 64 +                     \
                                       ((((ks << 2) + quad) ^ (lm & 7)) << 3)];\
  }                                                                            \
} while (0)

#define LDB_READ(BP, NH) do {                                                  \
  const u16* _p = (BP);                                                        \
  _Pragma("unroll") for (int ni = 0; ni < 2; ++ni) {                           \
    const int _rho = (NH) * 128 + wc * 32 + ni * 16 + lm;                      \
    _Pragma("unroll") for (int ks = 0; ks < 2; ++ks)                           \
      bfr[NH][ni][ks] = *(const bf16x8*)&_p[(size_t)_rho * 64 +                \
                                       ((((ks << 2) + quad) ^ (lm & 7)) << 3)];\
  }                                                                            \
} while (0)

#define MFMA_Q(MH, NH) do {                                                    \
  _Pragma("unroll") for (int mi = 0; mi < 4; ++mi)                             \
    _Pragma("unroll") for (int ni = 0; ni < 2; ++ni)                           \
      _Pragma("unroll") for (int ks = 0; ks < 2; ++ks)                         \
        acc[(MH) * 4 + mi][(NH) * 2 + ni] =                                    \
            __builtin_amdgcn_mfma_f32_16x16x32_bf16(                           \
                af[mi][ks], bfr[NH][ni][ks],                                   \
                acc[(MH) * 4 + mi][(NH) * 2 + ni], 0, 0, 0);                   \
} while (0)

__global__ __launch_bounds__(512, 2) void gemm256_rope_kernel(
    const u16* __restrict__ A, const u16* __restrict__ Bw,
    const float* __restrict__ bias, u16* __restrict__ C,
    int M, int N, int K, int lda, int ldb, int ldc)
{
  __shared__ u16 lds[2][2][256 * 64];   // [buf][A/B][storage] = 128 KB
  const int t = threadIdx.x;
  const int lane = t & 63, wid = t >> 6;
  const int wr = wid >> 2, wc = wid & 3;         // 2M x 4N wave grid
  const int quad = lane >> 4, lm = lane & 15;

  // T1: bijective XCD-chunked swizzle (nwg % 8 == 0), bx-major decode.
  const int nwg = gridDim.x * gridDim.y;
  const int lid = blockIdx.y * gridDim.x + blockIdx.x;
  const int sb = (lid & 7) * (nwg >> 3) + (lid >> 3);
  const int m0 = (sb % gridDim.y) * 256, n0 = (sb / gridDim.y) * 256;

  u16* As0 = &lds[0][0][0]; u16* Bs0 = &lds[0][1][0];
  u16* As1 = &lds[1][0][0]; u16* Bs1 = &lds[1][1][0];

  f32x4 acc[8][4] = {};
  bf16x8 af[4][2];         // current A quadrant [mi][ks]
  bf16x8 bfr[2][2][2];     // [nh][ni][ks], both halves live

  const int NT = K >> 6;   // K-tiles of 64

  // prologue: K-tile0 {A0,B0,B1,A1}, K-tile1 {A0,B0,B1}; K-tile1.A1 at ph1.
  stage_half<1>(A,  As0, 0, m0, 0, lda, wid, lane);
  stage_half<0>(Bw, Bs0, 0, n0, 0, ldb, wid, lane);
  stage_half<0>(Bw, Bs0, 1, n0, 0, ldb, wid, lane);
  stage_half<1>(A,  As0, 1, m0, 0, lda, wid, lane);
  asm volatile("s_waitcnt vmcnt(4)" ::: "memory");
  stage_half<1>(A,  As1, 0, m0, 64, lda, wid, lane);
  stage_half<0>(Bw, Bs1, 0, n0, 64, ldb, wid, lane);
  stage_half<0>(Bw, Bs1, 1, n0, 64, ldb, wid, lane);
  asm volatile("s_waitcnt vmcnt(6)" ::: "memory");
  BAR();

  for (int it2 = 0; it2 < (NT >> 1); ++it2) {
    int kb1 = (it2 * 2 + 1) << 6;                       // always < K
    int kb2 = (it2 * 2 + 2) << 6; if (kb2 >= K) kb2 -= K;  // wrap: safe garbage
    int kb3 = (it2 * 2 + 3) << 6; if (kb3 >= K) kb3 -= K;

    // ph1: read A0,B0 (buf0); stage (2t+1).A1 -> As1
    LDA_READ(As0, 0); LDB_READ(Bs0, 0);
    stage_half<1>(A, As1, 1, m0, kb1, lda, wid, lane);
    BAR(); PRIO1(); MFMA_Q(0, 0); PRIO0(); BAR();
    // ph2: read B1 (buf0); stage (2t+2).A0 -> As0
    LDB_READ(Bs0, 1);
    stage_half<1>(A, As0, 0, m0, kb2, lda, wid, lane);
    BAR(); PRIO1(); MFMA_Q(0, 1); PRIO0(); BAR();
    // ph3: read A1 (buf0); stage (2t+2).B0 -> Bs0
    LDA_READ(As0, 1);
    stage_half<0>(Bw, Bs0, 0, n0, kb2, ldb, wid, lane);
    BAR(); PRIO1(); MFMA_Q(1, 1); PRIO0(); BAR();
    // ph4: stage (2t+2).B1 -> Bs0; counted wait: K-tile 2t+1 fully landed
    stage_half<0>(Bw, Bs0, 1, n0, kb2, ldb, wid, lane);
    asm volatile("s_waitcnt vmcnt(6)" ::: "memory");
    BAR(); PRIO1(); MFMA_Q(1, 0); PRIO0(); BAR();
    // ph5: read A0,B0 (buf1); stage (2t+2).A1 -> As0
    LDA_READ(As1, 0); LDB_READ(Bs1, 0);
    stage_half<1>(A, As0, 1, m0, kb2, lda, wid, lane);
    BAR(); PRIO1(); MFMA_Q(0, 0); PRIO0(); BAR();
    // ph6: read B1 (buf1); stage (2t+3).A0 -> As1
    LDB_READ(Bs1, 1);
    stage_half<1>(A, As1, 0, m0, kb3, lda, wid, lane);
    BAR(); PRIO1(); MFMA_Q(0, 1); PRIO0(); BAR();
    // ph7: read A1 (buf1); stage (2t+3).B0 -> Bs1
    LDA_READ(As1, 1);
    stage_half<0>(Bw, Bs1, 0, n0, kb3, ldb, wid, lane);
    BAR(); PRIO1(); MFMA_Q(1, 1); PRIO0(); BAR();
    // ph8: stage (2t+3).B1 -> Bs1; counted wait: K-tile 2t+2 fully landed
    stage_half<0>(Bw, Bs1, 1, n0, kb3, ldb, wid, lane);
    asm volatile("s_waitcnt vmcnt(6)" ::: "memory");
    BAR(); PRIO1(); MFMA_Q(1, 0); PRIO0(); BAR();
  }
  // drain in-flight LDS DMA before waves exit (LDS dealloc hazard)
  asm volatile("s_waitcnt vmcnt(0)" ::: "memory");

  // epilogue: bias (+RoPE on head-cols 0..31 for Q,K) -> bf16 store
  const int cbase = n0 + wc * 64;
  const float ropefreq = exp2f(-(float)lm * 0.8304820237218406f);
  const bool do_rope = ((wc & 1) == 0) && (cbase < 4096);
  float b0 = 0.f, b1 = 0.f;
  if (do_rope) { b0 = bias[cbase + lm]; b1 = bias[cbase + lm + 16]; }

#pragma unroll
  for (int mi8 = 0; mi8 < 8; ++mi8) {
    const int gm = m0 + wr * 128 + mi8 * 16 + quad * 4;
    int jstart = 0;
    if (do_rope) {
      jstart = 2;
      const int gn0 = cbase + lm, gn1 = gn0 + 16;
#pragma unroll
      for (int rg = 0; rg < 4; ++rg) {
        int rs = gm + rg;
        float sn, cs;
        __sincosf((float)(rs & (SS - 1)) * ropefreq, &sn, &cs);
        float x0 = acc[mi8][0][rg] + b0, x1 = acc[mi8][1][rg] + b1;
        C[(size_t)rs * ldc + gn0] = f2b(x0 * cs - x1 * sn);
        C[(size_t)rs * ldc + gn1] = f2b(x1 * cs + x0 * sn);
      }
    }
#pragma unroll
    for (int nj = 0; nj < 4; ++nj) {
      if (nj < jstart) continue;
      const int gn = cbase + nj * 16 + lm;
      if (gn < N) {
        f32x4 a = acc[mi8][nj];
        float bs = bias[gn];
#pragma unroll
        for (int rg = 0; rg < 4; ++rg)
          C[(size_t)(gm + rg) * ldc + gn] = f2b(a[rg] + bs);
      }
    }
  }
}

// C = A[M,K](bf16) @ Bw[N,K](bf16)^T + bias(f32). OUT_F32 ? f32 : bf16 store.
// BIAS_ROW: bias indexed by output row. NOBIAS: no bias add (weight-fold GEMM).
// blockIdx.z batching via strideB/strideC (elements).
template<int OUT_F32, int ROPE, int BIAS_ROW, int NOBIAS>
__global__ __launch_bounds__(256) void gemm_bias_kernel(
    const u16* __restrict__ A, const u16* __restrict__ Bw,
    const float* __restrict__ bias, void* __restrict__ Cv,
    int M, int N, int K, int lda, int ldb, int ldc,
    size_t strideB, size_t strideC)
{
  __shared__ u16 Asf[128 * 4 * 8];   // [row][chunk][8]  8KB
  __shared__ u16 Bsf[128 * 4 * 8];
  const int t = threadIdx.x;
  const int m0 = blockIdx.y * 128;
  const int n0 = blockIdx.x * 128;
  const int lane = t & 63, wid = t >> 6;
  const int wm = (wid >> 1) * 64, wn = (wid & 1) * 64;
  const int quad = lane >> 4, lm = lane & 15;

  const u16* Bz = Bw + (size_t)blockIdx.z * strideB;

  // staging lane decomposition: lane = r16*4 + c  (16 rows x 4 chunks per gload)
  const int r16 = lane >> 2;
  const int swz = ((lane >> 2) & 3) ^ ((lane >> 4) & 3);
  const int kc = ((lane & 3) ^ swz) * 8;     // swizzled k-chunk (element offset)
  const int fswz = (lm & 3) ^ ((lm >> 2) & 3);

  f32x4 acc[4][4] = {};

  for (int k0 = 0; k0 < K; k0 += 32) {
    __syncthreads();
#pragma unroll
    for (int it = 0; it < 2; ++it) {
      int g = wid * 2 + it;                  // 16-row group 0..7
      int r = g * 16 + r16;
      gload_lds16(A + (size_t)(m0 + r) * lda + k0 + kc, &Asf[(size_t)g * 512]);
      gload_lds16(Bz + (size_t)(n0 + r) * ldb + k0 + kc, &Bsf[(size_t)g * 512]);
    }
    __syncthreads();
    bf16x8 af[4], bf[4];
#pragma unroll
    for (int i = 0; i < 4; ++i) {
      int row = wm + i * 16 + lm;
      af[i] = *(const bf16x8*)&Asf[(size_t)(row * 4 + (quad ^ fswz)) * 8];
    }
#pragma unroll
    for (int j = 0; j < 4; ++j) {
      int row = wn + j * 16 + lm;
      bf[j] = *(const bf16x8*)&Bsf[(size_t)(row * 4 + (quad ^ fswz)) * 8];
    }
#pragma unroll
    for (int i = 0; i < 4; ++i)
#pragma unroll
      for (int j = 0; j < 4; ++j)
        acc[i][j] = __builtin_amdgcn_mfma_f32_16x16x32_bf16(af[i], bf[j], acc[i][j], 0, 0, 0);
  }

  float* Cf = (float*)Cv + (OUT_F32 ? (size_t)blockIdx.z * strideC : 0);
  u16* Cu = (u16*)Cv + (OUT_F32 ? 0 : (size_t)blockIdx.z * strideC);
  const float ropefreq = ROPE ? exp2f(-(float)lm * 0.8304820237218406f) : 0.f;
  const bool do_rope = ROPE && (wn == 0) && (n0 < 4096);

#pragma unroll
  for (int i = 0; i < 4; ++i) {
    int gm = m0 + wm + i * 16 + quad * 4;
    int jstart = 0;
    if (do_rope) {
      jstart = 2;
      int gn0 = n0 + lm, gn1 = gn0 + 16;
      float b0 = bias[gn0], b1 = bias[gn1];
#pragma unroll
      for (int rg = 0; rg < 4; ++rg) {
        int rs = gm + rg;
        float sn, cs;
        __sincosf((float)(rs & (SS - 1)) * ropefreq, &sn, &cs);
        float x0 = acc[i][0][rg] + b0, x1 = acc[i][1][rg] + b1;
        Cu[(size_t)rs * ldc + gn0] = f2b(x0 * cs - x1 * sn);
        Cu[(size_t)rs * ldc + gn1] = f2b(x1 * cs + x0 * sn);
      }
    }
#pragma unroll
    for (int j = 0; j < 4; ++j) {
      if (j < jstart) continue;
      int gn = n0 + wn + j * 16 + lm;
      if (gn < N) {
        f32x4 a = acc[i][j];
#pragma unroll
        for (int rg = 0; rg < 4; ++rg) {
          float bsv = NOBIAS ? 0.f : (BIAS_ROW ? bias[gm + rg] : bias[gn]);
          if (OUT_F32) Cf[(size_t)(gm + rg) * ldc + gn] = a[rg] + bsv;
          else         Cu[(size_t)(gm + rg) * ldc + gn] = f2b(a[rg] + bsv);
        }
      }
    }
  }
}

// MFMA causal flash attention, S^T formulation. Block = 4 waves.
// 512 blocks; q-tile PAIR (31-pr, pr) -> uniform 33 k-tiles/block.
// Round-6: V-staging bank-conflict fix. Old Vt[kq][d] put all 8 lanes of
// each issue group (same d, kq=0..7) in ONE 16B bank slot (kq stride 2048B
// == 0 mod 128B) -> 8-way conflict on every V write = the entire 1.62e7
// SQ_LDS_BANK_CONFLICT. Store at Vt[kq][d ^ kq], read Vt[kq][(dt*16+lm)^kq]
// (same involution both sides; bijective per kq).
__global__ __launch_bounds__(256) void attn_mfma_kernel(
    const u16* __restrict__ qkv, const u16* __restrict__ vrt, u16* __restrict__ out)
{
  __shared__ u16 Kt[64 * 16 * 8];  // chunk(kp,dq) at kp*16 + (dq^(kp&15))   16KB
  __shared__ u16 Vt[8][128][8];    // [kq][d^kq][j] = V[kb+kq*8+j][d]        16KB
  __shared__ u16 Pa[4][16 * 64];   // [w][q*64 + unit-swizzled]               8KB

  const int t = threadIdx.x;
  const int lane = t & 63, w = t >> 6;
  const int quad = lane >> 4, lm = lane & 15;
  const int lid = blockIdx.x;          // 0..511
  const int sbx = (lid & 7) * 64 + (lid >> 3);   // XCD-chunked, bijective
  const int bh = sbx >> 4;             // 4 heads per XCD chunk
  const int pr = sbx & 15;             // pair index: q-tiles {31-pr, pr}
  const int b = bh >> 4, h = bh & 15;

  const float scale = 0.08838834764831845f;  // 1/sqrt(128)
  const u16* kbase = qkv + (size_t)b * SS * 6144 + 2048 + h * 128;
  const u16* vbase = vrt + (size_t)bh * 128 * 2048;
  u16* pw = &Pa[w][0];

#pragma unroll 1
  for (int ps = 0; ps < 2; ++ps) {
    const int qt = ps ? pr : (31 - pr);
    const int qw = qt * 64 + w * 16;
    const int nkt = qt + 1;

    // Q fragments (B-operand): Q[qw+lm][dc*32+quad*8+j]
    bf16x8 qf[4];
    {
      const u16* qsrc = qkv + (size_t)(b * SS + qw + lm) * 6144 + h * 128 + quad * 8;
#pragma unroll
      for (int dc = 0; dc < 4; ++dc) qf[dc] = *(const bf16x8*)(qsrc + dc * 32);
    }

    f32x4 Oa[8] = {};                 // [dt]: O[q=quad*4+r][d=dt*16+lm]
    float m_i = -1e30f, l_i = 0.f;    // per-lane softmax state for q = qw+lm

#pragma unroll 1
    for (int kt = 0; kt < nkt; ++kt) {
      const int kb = kt * 64;
      __syncthreads();
#pragma unroll
      for (int it = 0; it < 4; ++it) {
        int c = t + it * 256;
        int kp = c >> 4, dq = c & 15;
        *(uint4*)&Kt[(size_t)(kp * 16 + (dq ^ (kp & 15))) * 8] =
            *(const uint4*)(kbase + (size_t)(kb + kp) * 6144 + dq * 8);
        int d = c >> 3, kq = c & 7;
        *(uint4*)&Vt[kq][d ^ kq][0] =
            *(const uint4*)(vbase + (size_t)d * 2048 + kb + kq * 8);
      }
      __syncthreads();

      // S^T = K Q^T : C-layout col = q (lane&15), row = kpos_local = quad*4+r
      f32x4 sa[4] = {};
#pragma unroll
      for (int ct = 0; ct < 4; ++ct) {
#pragma unroll
        for (int dc = 0; dc < 4; ++dc) {
          bf16x8 kf = *(const bf16x8*)&Kt[(size_t)((ct * 16 + lm) * 16 +
                                                   ((dc * 4 + quad) ^ lm)) * 8];
          sa[ct] = __builtin_amdgcn_mfma_f32_16x16x32_bf16(kf, qf[dc], sa[ct], 0, 0, 0);
        }
      }
#pragma unroll
      for (int ct = 0; ct < 4; ++ct)
#pragma unroll
        for (int r = 0; r < 4; ++r) sa[ct][r] *= scale;

      if (kt == nkt - 1) {  // diagonal tile: mask kpos > q
        int qpos = qw + lm;
#pragma unroll
        for (int ct = 0; ct < 4; ++ct) {
#pragma unroll
          for (int r = 0; r < 4; ++r)
            if (kb + ct * 16 + quad * 4 + r > qpos) sa[ct][r] = -1e30f;
        }
      }

      // online softmax, per-lane row q = qw+lm
      float mx = sa[0][0];
#pragma unroll
      for (int ct = 0; ct < 4; ++ct)
#pragma unroll
        for (int r = 0; r < 4; ++r) mx = fmaxf(mx, sa[ct][r]);
      mx = fmaxf(mx, __shfl_xor(mx, 16, 64));
      mx = fmaxf(mx, __shfl_xor(mx, 32, 64));
      float mnew = fmaxf(m_i, mx);
      float alpha = __expf(m_i - mnew);
      float ssum = 0.f;
#pragma unroll
      for (int ct = 0; ct < 4; ++ct)
#pragma unroll
        for (int r = 0; r < 4; ++r) {
          float p = __expf(sa[ct][r] - mnew);
          sa[ct][r] = p;
          ssum += p;
        }
      ssum += __shfl_xor(ssum, 16, 64);
      ssum += __shfl_xor(ssum, 32, 64);
      l_i = l_i * alpha + ssum;
      m_i = mnew;

      // redistribute alpha to O rows (q = quad*4+r held at lane lm' = quad*4+r)
      float ar[4];
#pragma unroll
      for (int r = 0; r < 4; ++r) ar[r] = __shfl(alpha, quad * 4 + r, 64);
#pragma unroll
      for (int dt = 0; dt < 8; ++dt)
#pragma unroll
        for (int r = 0; r < 4; ++r) Oa[dt][r] *= ar[r];

      // P^T (C-layout) -> Pa A-frag layout
#pragma unroll
      for (int ct = 0; ct < 4; ++ct) {
        uint2 pk;
        pk.x = (u32)f2b(sa[ct][0]) | ((u32)f2b(sa[ct][1]) << 16);
        pk.y = (u32)f2b(sa[ct][2]) | ((u32)f2b(sa[ct][3]) << 16);
        int u = ct * 2 + (quad >> 1);
        *(uint2*)(pw + lm * 64 + ((u ^ (lm & 7)) * 8) + (quad & 1) * 4) = pk;
      }
      bf16x8 pf0 = *(const bf16x8*)(pw + lm * 64 + ((quad ^ (lm & 7)) * 8));
      bf16x8 pf1 = *(const bf16x8*)(pw + lm * 64 + (((4 + quad) ^ (lm & 7)) * 8));

      // O += P V
#pragma unroll
      for (int dt = 0; dt < 8; ++dt) {
        bf16x8 vf0 = *(const bf16x8*)&Vt[quad][(dt * 16 + lm) ^ quad][0];
        bf16x8 vf1 = *(const bf16x8*)&Vt[4 + quad][(dt * 16 + lm) ^ (4 + quad)][0];
        Oa[dt] = __builtin_amdgcn_mfma_f32_16x16x32_bf16(pf0, vf0, Oa[dt], 0, 0, 0);
        Oa[dt] = __builtin_amdgcn_mfma_f32_16x16x32_bf16(pf1, vf1, Oa[dt], 0, 0, 0);
      }
    }

    float inv = 1.0f / l_i;
    float ir[4];
#pragma unroll
    for (int r = 0; r < 4; ++r) ir[r] = __shfl(inv, quad * 4 + r, 64);
    u16* dst = out + (size_t)(b * SS + qw + quad * 4) * 2048 + h * 128 + lm;
#pragma unroll
    for (int r = 0; r < 4; ++r)
#pragma unroll
      for (int dt = 0; dt < 8; ++dt)
        dst[(size_t)r * 2048 + dt * 16] = f2b(Oa[dt][r] * ir[r]);
  }
}

extern "C" void kernel_launch(void* const* d_in, const int* in_sizes, int n_in,
                              void* d_out, int out_size, void* d_ws, size_t ws_size,
                              hipStream_t stream)
{
  (void)in_sizes; (void)n_in; (void)out_size; (void)ws_size;
  const float* X    = (const float*)d_in[0];
  const float* Wqkv = (const float*)d_in[1];
  const float* bqkv = (const float*)d_in[2];
  const float* Wc   = (const float*)d_in[3];
  const float* bc   = (const float*)d_in[4];
  const float* Wr   = (const float*)d_in[5];
  const float* br   = (const float*)d_in[6];
  const float* Wd   = (const float*)d_in[7];
  const float* bd   = (const float*)d_in[8];
  float* out = (float*)d_out;

  char* ws = (char*)d_ws;
  u16* QKV   = (u16*)(ws);                  // 48 MB  [1-5] (V third unused)
  u16* Xb    = (u16*)(ws + 50331648);       // 16 MB  [cvt-..]
  u16* AO    = (u16*)(ws + 50331648);       //        [attn-5]
  u16* Wqkvb = (u16*)(ws + 67108864);       // 24 MB  [cvt-1]
  u16* VrT   = (u16*)(ws + 67108864);       // 16 MB  [3-4] (aliases Wqkvb)
  u16* Wcb   = (u16*)(ws + 92274688);       // 1.25 MB
  u16* Wrb   = (u16*)(ws + 93585408);       // 1.25 MB
  u16* Cb    = (u16*)(ws + 94896128);       // 2.5 MB
  u16* Wdb   = (u16*)(ws + 97517568);       // 8 MB
  u16* WvTb  = (u16*)(ws + 105906176);      // 8 MB   Wv^T bf16
  u16* Wvc   = (u16*)(ws + 114294784);      // 1.5 MB (384x2048, rows 320+ junk)
  float* bc2 = (float*)(ws + 115867648);    // 1.25 KB

  dim3 blk(256);

  // 0. convert f32 inputs -> bf16
  cvt_kernel<<<dim3(512, 5), blk, 0, stream>>>(
      X, Xb, 4096 * 2048,
      Wqkv, Wqkvb, 6144 * 2048,
      Wc, Wcb, 320 * 2048,
      Wr, Wrb, 2048 * 320,
      Wd, Wdb, 2048 * 2048);

  // 0b. WvT = Wv^T (bf16), from f32 Wqkv rows 4096..6143
  transpose_wv_kernel<<<dim3(32, 32), blk, 0, stream>>>(Wqkv, WvTb);
  // 0c. bc2 = bc + Wc @ bv
  bc2_kernel<<<dim3(80), blk, 0, stream>>>(Wcb, bqkv, bc, bc2);
  // 0d. Wvc = Wc @ Wv  (= Wc @ WvT^T), no bias. Rows 320..383 of A are junk
  //     reads into Wrb (in-bounds); output rows 320..383 junk, never used.
  gemm_bias_kernel<0, 0, 0, 1><<<dim3(16, 3), blk, 0, stream>>>(
      Wcb, WvTb, bc, Wvc, 320, 2048, 2048, 2048, 2048, 2048, 0, 0);

  // 1. QK projection with fused RoPE — N=4096, 256 blocks = one exact round
  gemm256_rope_kernel<<<dim3(16, 16), dim3(512), 0, stream>>>(
      Xb, Wqkvb, bqkv, QKV, 4096, 4096, 2048, 2048, 2048, 6144);
  // 2. Cb = X @ Wvc^T + bc2   (V projection folded: == V_hidden @ Wc^T + bc)
  gemm_bias_kernel<0, 0, 0, 0><<<dim3(3, 32), blk, 0, stream>>>(
      Xb, Wvc, bc2, Cb, 4096, 320, 2048, 2048, 2048, 320, 0, 0);
  // 3. VrT = (Cb @ Wr^T)^T + br  == Wr @ Cb^T, per batch (z=2)
  gemm_bias_kernel<0, 0, 1, 0><<<dim3(16, 16, 2), blk, 0, stream>>>(
      Wrb, Cb, br, VrT, 2048, 2048, 320, 320, 320, 2048,
      (size_t)2048 * 320, (size_t)4194304);
  // 4. MFMA causal flash attention -> AO (bf16, hidden layout), paired q-tiles
  attn_mfma_kernel<<<dim3(512), blk, 0, stream>>>(QKV, VrT, AO);
  // 5. output projection -> f32 d_out
  gemm_bias_kernel<1, 0, 0, 0><<<dim3(16, 32), blk, 0, stream>>>(
      AO, Wdb, bd, out, 4096, 2048, 2048, 2048, 2048, 2048, 0, 0);
}

// Round 7
// 469.096 us; speedup vs baseline: 1.0442x; 1.0011x over previous
//
#include <hip/hip_runtime.h>

typedef unsigned short u16;
typedef unsigned int u32;
typedef __bf16 bf16x8 __attribute__((ext_vector_type(8)));
typedef float f32x4 __attribute__((ext_vector_type(4)));

#define BB 2
#define SS 2048
#define HH 2048
#define NHH 16
#define HDD 128

__device__ __forceinline__ float b2f(u16 u) {
  union { u32 i; float f; } v; v.i = ((u32)u) << 16; return v.f;
}
__device__ __forceinline__ u16 f2b(float f) {
  union { float f; u32 i; } v; v.f = f;
  u32 x = v.i;
  u32 r = (x + 0x7fffu + ((x >> 16) & 1u)) >> 16;
  return (u16)r;
}

// async global->LDS 16B: LDS dest = wave-uniform base + lane*16
__device__ __forceinline__ void gload_lds16(const u16* g, u16* l) {
  __builtin_amdgcn_global_load_lds(
      (const __attribute__((address_space(1))) u32*)g,
      (__attribute__((address_space(3))) u32*)l, 16, 0, 0);
}

// Fused f32 -> bf16 conversion for 5 tensors; blockIdx.y selects tensor.
__global__ __launch_bounds__(256) void cvt_kernel(
    const float* __restrict__ s0, u16* __restrict__ d0, int n0,
    const float* __restrict__ s1, u16* __restrict__ d1, int n1,
    const float* __restrict__ s2, u16* __restrict__ d2, int n2,
    const float* __restrict__ s3, u16* __restrict__ d3, int n3,
    const float* __restrict__ s4, u16* __restrict__ d4, int n4)
{
  const float* s; u16* d; int n;
  switch (blockIdx.y) {
    case 0: s = s0; d = d0; n = n0; break;
    case 1: s = s1; d = d1; n = n1; break;
    case 2: s = s2; d = d2; n = n2; break;
    case 3: s = s3; d = d3; n = n3; break;
    default: s = s4; d = d4; n = n4; break;
  }
  int nq = n >> 2;
  for (int q = blockIdx.x * 256 + threadIdx.x; q < nq; q += gridDim.x * 256) {
    float4 v = *(const float4*)(s + (size_t)q * 4);
    ushort4 o;
    o.x = f2b(v.x); o.y = f2b(v.y); o.z = f2b(v.z); o.w = f2b(v.w);
    *(ushort4*)(d + (size_t)q * 4) = o;
  }
}

// Transpose-convert Wv (rows 4096..6143 of f32 Wqkv) -> bf16 WvT[n][k] = Wv[k][n]
__global__ __launch_bounds__(256) void transpose_wv_kernel(
    const float* __restrict__ Wqkv, u16* __restrict__ WvT)
{
  __shared__ float tile[64][65];
  const int t = threadIdx.x;
  const int r0 = blockIdx.y * 64;   // Wv row block (k-index of WvT)
  const int c0 = blockIdx.x * 64;   // Wv col block (n-index of WvT)
  const int tr = t >> 4;            // 0..15
  const int tc = (t & 15) * 4;      // 0,4,..,60
#pragma unroll
  for (int i = 0; i < 4; ++i) {
    int r = tr + i * 16;
    float4 v = *(const float4*)(Wqkv + (size_t)(4096 + r0 + r) * 2048 + c0 + tc);
    tile[r][tc] = v.x; tile[r][tc + 1] = v.y; tile[r][tc + 2] = v.z; tile[r][tc + 3] = v.w;
  }
  __syncthreads();
#pragma unroll
  for (int i = 0; i < 4; ++i) {
    int n = tr + i * 16;            // col of Wv = output row
    ushort4 o;
    o.x = f2b(tile[tc + 0][n]);
    o.y = f2b(tile[tc + 1][n]);
    o.z = f2b(tile[tc + 2][n]);
    o.w = f2b(tile[tc + 3][n]);
    *(ushort4*)(WvT + (size_t)(c0 + n) * 2048 + r0 + tc) = o;
  }
}

// bc2[row] = bc[row] + dot(Wc[row,:], bv)   (320 rows; 80 blocks x 4 waves)
__global__ __launch_bounds__(256) void bc2_kernel(
    const u16* __restrict__ Wcb, const float* __restrict__ bqkv,
    const float* __restrict__ bc, float* __restrict__ bc2)
{
  const int t = threadIdx.x;
  const int lane = t & 63, w = t >> 6;
  const int row = blockIdx.x * 4 + w;
  const float* bv = bqkv + 4096;
  float s = 0.f;
  for (int j = lane; j < 2048; j += 64)
    s += b2f(Wcb[(size_t)row * 2048 + j]) * bv[j];
#pragma unroll
  for (int o = 32; o; o >>= 1) s += __shfl_xor(s, o, 64);
  if (lane == 0) bc2[row] = bc[row] + s;
}

// ---------------------------------------------------------------------------
// 256x256 8-phase GEMM (T1..T5 stack, m201 template) for the QK projection.
// N=4096 (V folded into Wvc) -> grid 16x16 = 256 blocks = one exact round.
// ---------------------------------------------------------------------------

template<int ISA>
__device__ __forceinline__ void stage_half(
    const u16* __restrict__ src, u16* ldsmat, int h,
    int tb, int kb, int ld, int wid, int lane)
{
#pragma unroll
  for (int l = 0; l < 2; ++l) {
    const int i = wid * 2 + l;
    const int rp = i * 8 + (lane >> 3);      // storage row within half, 0..127
    int r;
    if (ISA) r = (rp & 63) + ((rp >> 6) << 7) + h * 64;
    else     r = ((rp >> 5) << 6) + h * 32 + (rp & 31);
    const int c = (lane & 7) ^ (lane >> 3);  // inverse-swizzled global chunk
    gload_lds16(src + (size_t)(tb + r) * ld + kb + c * 8,
                ldsmat + (size_t)(h * 128 + i * 8) * 64);
  }
}

#define BAR()   __builtin_amdgcn_s_barrier()
#define PRIO1() __builtin_amdgcn_s_setprio(1)
#define PRIO0() __builtin_amdgcn_s_setprio(0)

#define LDA_READ(BP, MH) do {                                                  \
  const u16* _p = (BP);                                                        \
  _Pragma("unroll") for (int mi = 0; mi < 4; ++mi) {                           \
    const int _rho = (MH) * 128 + wr * 64 + mi * 16 + lm;                      \
    _Pragma("unroll") for (int ks = 0; ks < 2; ++ks)                           \
      af[mi][ks] = *(const bf16x8*)&_p[(size_t)_rho * 64 +                     \
                                       ((((ks << 2) + quad) ^ (lm & 7)) << 3)];\
  }                                                                            \
} while (0)

#define LDB_READ(BP, NH) do {                                                  \
  const u16* _p = (BP);                                                        \
  _Pragma("unroll") for (int ni = 0; ni < 2; ++ni) {                           \
    const int _rho = (NH) * 128 + wc * 32 + ni * 16 + lm;                      \
    _Pragma("unroll") for (int ks = 0; ks < 2; ++ks)                           \
      bfr[NH][ni][ks] = *(const bf16x8*)&_p[(size_t)_rho * 64 +                \
                                       ((((ks << 2) + quad) ^ (lm & 7)) << 3)];\
  }                                                                            \
} while (0)

#define MFMA_Q(MH, NH) do {                                                    \
  _Pragma("unroll") for (int mi = 0; mi < 4; ++mi)                             \
    _Pragma("unroll") for (int ni = 0; ni < 2; ++ni)                           \
      _Pragma("unroll") for (int ks = 0; ks < 2; ++ks)                         \
        acc[(MH) * 4 + mi][(NH) * 2 + ni] =                                    \
            __builtin_amdgcn_mfma_f32_16x16x32_bf16(                           \
                af[mi][ks], bfr[NH][ni][ks],                                   \
                acc[(MH) * 4 + mi][(NH) * 2 + ni], 0, 0, 0);                   \
} while (0)

__global__ __launch_bounds__(512, 2) void gemm256_rope_kernel(
    const u16* __restrict__ A, const u16* __restrict__ Bw,
    const float* __restrict__ bias, u16* __restrict__ C,
    int M, int N, int K, int lda, int ldb, int ldc)
{
  __shared__ u16 lds[2][2][256 * 64];   // [buf][A/B][storage] = 128 KB
  const int t = threadIdx.x;
  const int lane = t & 63, wid = t >> 6;
  const int wr = wid >> 2, wc = wid & 3;         // 2M x 4N wave grid
  const int quad = lane >> 4, lm = lane & 15;

  // T1: bijective XCD-chunked swizzle (nwg % 8 == 0), bx-major decode.
  const int nwg = gridDim.x * gridDim.y;
  const int lid = blockIdx.y * gridDim.x + blockIdx.x;
  const int sb = (lid & 7) * (nwg >> 3) + (lid >> 3);
  const int m0 = (sb % gridDim.y) * 256, n0 = (sb / gridDim.y) * 256;

  u16* As0 = &lds[0][0][0]; u16* Bs0 = &lds[0][1][0];
  u16* As1 = &lds[1][0][0]; u16* Bs1 = &lds[1][1][0];

  f32x4 acc[8][4] = {};
  bf16x8 af[4][2];         // current A quadrant [mi][ks]
  bf16x8 bfr[2][2][2];     // [nh][ni][ks], both halves live

  const int NT = K >> 6;   // K-tiles of 64

  // prologue: K-tile0 {A0,B0,B1,A1}, K-tile1 {A0,B0,B1}; K-tile1.A1 at ph1.
  stage_half<1>(A,  As0, 0, m0, 0, lda, wid, lane);
  stage_half<0>(Bw, Bs0, 0, n0, 0, ldb, wid, lane);
  stage_half<0>(Bw, Bs0, 1, n0, 0, ldb, wid, lane);
  stage_half<1>(A,  As0, 1, m0, 0, lda, wid, lane);
  asm volatile("s_waitcnt vmcnt(4)" ::: "memory");
  stage_half<1>(A,  As1, 0, m0, 64, lda, wid, lane);
  stage_half<0>(Bw, Bs1, 0, n0, 64, ldb, wid, lane);
  stage_half<0>(Bw, Bs1, 1, n0, 64, ldb, wid, lane);
  asm volatile("s_waitcnt vmcnt(6)" ::: "memory");
  BAR();

  for (int it2 = 0; it2 < (NT >> 1); ++it2) {
    int kb1 = (it2 * 2 + 1) << 6;                       // always < K
    int kb2 = (it2 * 2 + 2) << 6; if (kb2 >= K) kb2 -= K;  // wrap: safe garbage
    int kb3 = (it2 * 2 + 3) << 6; if (kb3 >= K) kb3 -= K;

    // ph1: read A0,B0 (buf0); stage (2t+1).A1 -> As1
    LDA_READ(As0, 0); LDB_READ(Bs0, 0);
    stage_half<1>(A, As1, 1, m0, kb1, lda, wid, lane);
    BAR(); PRIO1(); MFMA_Q(0, 0); PRIO0(); BAR();
    // ph2: read B1 (buf0); stage (2t+2).A0 -> As0
    LDB_READ(Bs0, 1);
    stage_half<1>(A, As0, 0, m0, kb2, lda, wid, lane);
    BAR(); PRIO1(); MFMA_Q(0, 1); PRIO0(); BAR();
    // ph3: read A1 (buf0); stage (2t+2).B0 -> Bs0
    LDA_READ(As0, 1);
    stage_half<0>(Bw, Bs0, 0, n0, kb2, ldb, wid, lane);
    BAR(); PRIO1(); MFMA_Q(1, 1); PRIO0(); BAR();
    // ph4: stage (2t+2).B1 -> Bs0; counted wait: K-tile 2t+1 fully landed
    stage_half<0>(Bw, Bs0, 1, n0, kb2, ldb, wid, lane);
    asm volatile("s_waitcnt vmcnt(6)" ::: "memory");
    BAR(); PRIO1(); MFMA_Q(1, 0); PRIO0(); BAR();
    // ph5: read A0,B0 (buf1); stage (2t+2).A1 -> As0
    LDA_READ(As1, 0); LDB_READ(Bs1, 0);
    stage_half<1>(A, As0, 1, m0, kb2, lda, wid, lane);
    BAR(); PRIO1(); MFMA_Q(0, 0); PRIO0(); BAR();
    // ph6: read B1 (buf1); stage (2t+3).A0 -> As1
    LDB_READ(Bs1, 1);
    stage_half<1>(A, As1, 0, m0, kb3, lda, wid, lane);
    BAR(); PRIO1(); MFMA_Q(0, 1); PRIO0(); BAR();
    // ph7: read A1 (buf1); stage (2t+3).B0 -> Bs1
    LDA_READ(As1, 1);
    stage_half<0>(Bw, Bs1, 0, n0, kb3, ldb, wid, lane);
    BAR(); PRIO1(); MFMA_Q(1, 1); PRIO0(); BAR();
    // ph8: stage (2t+3).B1 -> Bs1; counted wait: K-tile 2t+2 fully landed
    stage_half<0>(Bw, Bs1, 1, n0, kb3, ldb, wid, lane);
    asm volatile("s_waitcnt vmcnt(6)" ::: "memory");
    BAR(); PRIO1(); MFMA_Q(1, 0); PRIO0(); BAR();
  }
  // drain in-flight LDS DMA before waves exit (LDS dealloc hazard)
  asm volatile("s_waitcnt vmcnt(0)" ::: "memory");

  // epilogue: bias (+RoPE on head-cols 0..31 for Q,K) -> bf16 store
  const int cbase = n0 + wc * 64;
  const float ropefreq = exp2f(-(float)lm * 0.8304820237218406f);
  const bool do_rope = ((wc & 1) == 0) && (cbase < 4096);
  float b0 = 0.f, b1 = 0.f;
  if (do_rope) { b0 = bias[cbase + lm]; b1 = bias[cbase + lm + 16]; }

#pragma unroll
  for (int mi8 = 0; mi8 < 8; ++mi8) {
    const int gm = m0 + wr * 128 + mi8 * 16 + quad * 4;
    int jstart = 0;
    if (do_rope) {
      jstart = 2;
      const int gn0 = cbase + lm, gn1 = gn0 + 16;
#pragma unroll
      for (int rg = 0; rg < 4; ++rg) {
        int rs = gm + rg;
        float sn, cs;
        __sincosf((float)(rs & (SS - 1)) * ropefreq, &sn, &cs);
        float x0 = acc[mi8][0][rg] + b0, x1 = acc[mi8][1][rg] + b1;
        C[(size_t)rs * ldc + gn0] = f2b(x0 * cs - x1 * sn);
        C[(size_t)rs * ldc + gn1] = f2b(x1 * cs + x0 * sn);
      }
    }
#pragma unroll
    for (int nj = 0; nj < 4; ++nj) {
      if (nj < jstart) continue;
      const int gn = cbase + nj * 16 + lm;
      if (gn < N) {
        f32x4 a = acc[mi8][nj];
        float bs = bias[gn];
#pragma unroll
        for (int rg = 0; rg < 4; ++rg)
          C[(size_t)(gm + rg) * ldc + gn] = f2b(a[rg] + bs);
      }
    }
  }
}

// C = A[M,K](bf16) @ Bw[N,K](bf16)^T + bias(f32). OUT_F32 ? f32 : bf16 store.
// BIAS_ROW: bias indexed by output row. NOBIAS: no bias add (weight-fold GEMM).
// blockIdx.z batching via strideB/strideC (elements).
template<int OUT_F32, int ROPE, int BIAS_ROW, int NOBIAS>
__global__ __launch_bounds__(256) void gemm_bias_kernel(
    const u16* __restrict__ A, const u16* __restrict__ Bw,
    const float* __restrict__ bias, void* __restrict__ Cv,
    int M, int N, int K, int lda, int ldb, int ldc,
    size_t strideB, size_t strideC)
{
  __shared__ u16 Asf[128 * 4 * 8];   // [row][chunk][8]  8KB
  __shared__ u16 Bsf[128 * 4 * 8];
  const int t = threadIdx.x;
  const int m0 = blockIdx.y * 128;
  const int n0 = blockIdx.x * 128;
  const int lane = t & 63, wid = t >> 6;
  const int wm = (wid >> 1) * 64, wn = (wid & 1) * 64;
  const int quad = lane >> 4, lm = lane & 15;

  const u16* Bz = Bw + (size_t)blockIdx.z * strideB;

  // staging lane decomposition: lane = r16*4 + c  (16 rows x 4 chunks per gload)
  const int r16 = lane >> 2;
  const int swz = ((lane >> 2) & 3) ^ ((lane >> 4) & 3);
  const int kc = ((lane & 3) ^ swz) * 8;     // swizzled k-chunk (element offset)
  const int fswz = (lm & 3) ^ ((lm >> 2) & 3);

  f32x4 acc[4][4] = {};

  for (int k0 = 0; k0 < K; k0 += 32) {
    __syncthreads();
#pragma unroll
    for (int it = 0; it < 2; ++it) {
      int g = wid * 2 + it;                  // 16-row group 0..7
      int r = g * 16 + r16;
      gload_lds16(A + (size_t)(m0 + r) * lda + k0 + kc, &Asf[(size_t)g * 512]);
      gload_lds16(Bz + (size_t)(n0 + r) * ldb + k0 + kc, &Bsf[(size_t)g * 512]);
    }
    __syncthreads();
    bf16x8 af[4], bf[4];
#pragma unroll
    for (int i = 0; i < 4; ++i) {
      int row = wm + i * 16 + lm;
      af[i] = *(const bf16x8*)&Asf[(size_t)(row * 4 + (quad ^ fswz)) * 8];
    }
#pragma unroll
    for (int j = 0; j < 4; ++j) {
      int row = wn + j * 16 + lm;
      bf[j] = *(const bf16x8*)&Bsf[(size_t)(row * 4 + (quad ^ fswz)) * 8];
    }
#pragma unroll
    for (int i = 0; i < 4; ++i)
#pragma unroll
      for (int j = 0; j < 4; ++j)
        acc[i][j] = __builtin_amdgcn_mfma_f32_16x16x32_bf16(af[i], bf[j], acc[i][j], 0, 0, 0);
  }

  float* Cf = (float*)Cv + (OUT_F32 ? (size_t)blockIdx.z * strideC : 0);
  u16* Cu = (u16*)Cv + (OUT_F32 ? 0 : (size_t)blockIdx.z * strideC);
  const float ropefreq = ROPE ? exp2f(-(float)lm * 0.8304820237218406f) : 0.f;
  const bool do_rope = ROPE && (wn == 0) && (n0 < 4096);

#pragma unroll
  for (int i = 0; i < 4; ++i) {
    int gm = m0 + wm + i * 16 + quad * 4;
    int jstart = 0;
    if (do_rope) {
      jstart = 2;
      int gn0 = n0 + lm, gn1 = gn0 + 16;
      float b0 = bias[gn0], b1 = bias[gn1];
#pragma unroll
      for (int rg = 0; rg < 4; ++rg) {
        int rs = gm + rg;
        float sn, cs;
        __sincosf((float)(rs & (SS - 1)) * ropefreq, &sn, &cs);
        float x0 = acc[i][0][rg] + b0, x1 = acc[i][1][rg] + b1;
        Cu[(size_t)rs * ldc + gn0] = f2b(x0 * cs - x1 * sn);
        Cu[(size_t)rs * ldc + gn1] = f2b(x1 * cs + x0 * sn);
      }
    }
#pragma unroll
    for (int j = 0; j < 4; ++j) {
      if (j < jstart) continue;
      int gn = n0 + wn + j * 16 + lm;
      if (gn < N) {
        f32x4 a = acc[i][j];
#pragma unroll
        for (int rg = 0; rg < 4; ++rg) {
          float bsv = NOBIAS ? 0.f : (BIAS_ROW ? bias[gm + rg] : bias[gn]);
          if (OUT_F32) Cf[(size_t)(gm + rg) * ldc + gn] = a[rg] + bsv;
          else         Cu[(size_t)(gm + rg) * ldc + gn] = f2b(a[rg] + bsv);
        }
      }
    }
  }
}

// MFMA causal flash attention, S^T formulation. Block = 4 waves.
// 512 blocks; q-tile PAIR (31-pr, pr) -> uniform 33 k-tiles/block.
// Round-7 VALU diet: exp2-domain softmax (scale*log2e folded into one fma),
// T13 defer-max (skip O-rescale when __all(mx - m <= 8/scale); P <= e^8,
// bf16-safe), T12 v_cvt_pk_bf16_f32 for the P pack (RNE, same as f2b).
__global__ __launch_bounds__(256) void attn_mfma_kernel(
    const u16* __restrict__ qkv, const u16* __restrict__ vrt, u16* __restrict__ out)
{
  __shared__ u16 Kt[64 * 16 * 8];  // chunk(kp,dq) at kp*16 + (dq^(kp&15))   16KB
  __shared__ u16 Vt[8][128][8];    // [kq][d^kq][j] = V[kb+kq*8+j][d]        16KB
  __shared__ u16 Pa[4][16 * 64];   // [w][q*64 + unit-swizzled]               8KB

  const int t = threadIdx.x;
  const int lane = t & 63, w = t >> 6;
  const int quad = lane >> 4, lm = lane & 15;
  const int lid = blockIdx.x;          // 0..511
  const int sbx = (lid & 7) * 64 + (lid >> 3);   // XCD-chunked, bijective
  const int bh = sbx >> 4;             // 4 heads per XCD chunk
  const int pr = sbx & 15;             // pair index: q-tiles {31-pr, pr}
  const int b = bh >> 4, h = bh & 15;

  const float cc = 0.12751375877961766f;   // (1/sqrt(128)) * log2(e)
  const float THR_RAW = 90.50966799187809f; // 8 / (1/sqrt(128))
  const u16* kbase = qkv + (size_t)b * SS * 6144 + 2048 + h * 128;
  const u16* vbase = vrt + (size_t)bh * 128 * 2048;
  u16* pw = &Pa[w][0];

#pragma unroll 1
  for (int ps = 0; ps < 2; ++ps) {
    const int qt = ps ? pr : (31 - pr);
    const int qw = qt * 64 + w * 16;
    const int nkt = qt + 1;

    // Q fragments (B-operand): Q[qw+lm][dc*32+quad*8+j]
    bf16x8 qf[4];
    {
      const u16* qsrc = qkv + (size_t)(b * SS + qw + lm) * 6144 + h * 128 + quad * 8;
#pragma unroll
      for (int dc = 0; dc < 4; ++dc) qf[dc] = *(const bf16x8*)(qsrc + dc * 32);
    }

    f32x4 Oa[8] = {};                 // [dt]: O[q=quad*4+r][d=dt*16+lm]
    float m_i = -1e30f, l_i = 0.f;    // per-lane softmax state (RAW S units)

#pragma unroll 1
    for (int kt = 0; kt < nkt; ++kt) {
      const int kb = kt * 64;
      __syncthreads();
#pragma unroll
      for (int it = 0; it < 4; ++it) {
        int c = t + it * 256;
        int kp = c >> 4, dq = c & 15;
        *(uint4*)&Kt[(size_t)(kp * 16 + (dq ^ (kp & 15))) * 8] =
            *(const uint4*)(kbase + (size_t)(kb + kp) * 6144 + dq * 8);
        int d = c >> 3, kq = c & 7;
        *(uint4*)&Vt[kq][d ^ kq][0] =
            *(const uint4*)(vbase + (size_t)d * 2048 + kb + kq * 8);
      }
      __syncthreads();

      // S^T = K Q^T : C-layout col = q (lane&15), row = kpos_local = quad*4+r
      // (kept RAW; scale*log2e folded into the exp2 fma below)
      f32x4 sa[4] = {};
#pragma unroll
      for (int ct = 0; ct < 4; ++ct) {
#pragma unroll
        for (int dc = 0; dc < 4; ++dc) {
          bf16x8 kf = *(const bf16x8*)&Kt[(size_t)((ct * 16 + lm) * 16 +
                                                   ((dc * 4 + quad) ^ lm)) * 8];
          sa[ct] = __builtin_amdgcn_mfma_f32_16x16x32_bf16(kf, qf[dc], sa[ct], 0, 0, 0);
        }
      }

      if (kt == nkt - 1) {  // diagonal tile: mask kpos > q
        int qpos = qw + lm;
#pragma unroll
        for (int ct = 0; ct < 4; ++ct) {
#pragma unroll
          for (int r = 0; r < 4; ++r)
            if (kb + ct * 16 + quad * 4 + r > qpos) sa[ct][r] = -1e30f;
        }
      }

      // online softmax (raw units), per-lane row q = qw+lm
      float mx = sa[0][0];
#pragma unroll
      for (int ct = 0; ct < 4; ++ct)
#pragma unroll
        for (int r = 0; r < 4; ++r) mx = fmaxf(mx, sa[ct][r]);
      mx = fmaxf(mx, __shfl_xor(mx, 16, 64));
      mx = fmaxf(mx, __shfl_xor(mx, 32, 64));

      // T13 defer-max: only rescale when some row's max grew past THR
      float ls = 1.f;
      if (!__all(mx - m_i <= THR_RAW)) {
        float mnew = fmaxf(m_i, mx);
        float alpha = exp2f((m_i - mnew) * cc);
        float ar[4];
#pragma unroll
        for (int r = 0; r < 4; ++r) ar[r] = __shfl(alpha, quad * 4 + r, 64);
#pragma unroll
        for (int dt = 0; dt < 8; ++dt)
#pragma unroll
          for (int r = 0; r < 4; ++r) Oa[dt][r] *= ar[r];
        ls = alpha;
        m_i = mnew;
      }

      const float mc = m_i * cc;
      float ssum = 0.f;
#pragma unroll
      for (int ct = 0; ct < 4; ++ct)
#pragma unroll
        for (int r = 0; r < 4; ++r) {
          float p = exp2f(fmaf(sa[ct][r], cc, -mc));
          sa[ct][r] = p;
          ssum += p;
        }
      ssum += __shfl_xor(ssum, 16, 64);
      ssum += __shfl_xor(ssum, 32, 64);
      l_i = l_i * ls + ssum;

      // P^T (C-layout) -> Pa A-frag layout; pack via v_cvt_pk_bf16_f32 (RNE)
#pragma unroll
      for (int ct = 0; ct < 4; ++ct) {
        uint2 pk;
        asm("v_cvt_pk_bf16_f32 %0, %1, %2"
            : "=v"(pk.x) : "v"(sa[ct][0]), "v"(sa[ct][1]));
        asm("v_cvt_pk_bf16_f32 %0, %1, %2"
            : "=v"(pk.y) : "v"(sa[ct][2]), "v"(sa[ct][3]));
        int u = ct * 2 + (quad >> 1);
        *(uint2*)(pw + lm * 64 + ((u ^ (lm & 7)) * 8) + (quad & 1) * 4) = pk;
      }
      bf16x8 pf0 = *(const bf16x8*)(pw + lm * 64 + ((quad ^ (lm & 7)) * 8));
      bf16x8 pf1 = *(const bf16x8*)(pw + lm * 64 + (((4 + quad) ^ (lm & 7)) * 8));

      // O += P V
#pragma unroll
      for (int dt = 0; dt < 8; ++dt) {
        bf16x8 vf0 = *(const bf16x8*)&Vt[quad][(dt * 16 + lm) ^ quad][0];
        bf16x8 vf1 = *(const bf16x8*)&Vt[4 + quad][(dt * 16 + lm) ^ (4 + quad)][0];
        Oa[dt] = __builtin_amdgcn_mfma_f32_16x16x32_bf16(pf0, vf0, Oa[dt], 0, 0, 0);
        Oa[dt] = __builtin_amdgcn_mfma_f32_16x16x32_bf16(pf1, vf1, Oa[dt], 0, 0, 0);
      }
    }

    float inv = 1.0f / l_i;
    float ir[4];
#pragma unroll
    for (int r = 0; r < 4; ++r) ir[r] = __shfl(inv, quad * 4 + r, 64);
    u16* dst = out + (size_t)(b * SS + qw + quad * 4) * 2048 + h * 128 + lm;
#pragma unroll
    for (int r = 0; r < 4; ++r)
#pragma unroll
      for (int dt = 0; dt < 8; ++dt)
        dst[(size_t)r * 2048 + dt * 16] = f2b(Oa[dt][r] * ir[r]);
  }
}

extern "C" void kernel_launch(void* const* d_in, const int* in_sizes, int n_in,
                              void* d_out, int out_size, void* d_ws, size_t ws_size,
                              hipStream_t stream)
{
  (void)in_sizes; (void)n_in; (void)out_size; (void)ws_size;
  const float* X    = (const float*)d_in[0];
  const float* Wqkv = (const float*)d_in[1];
  const float* bqkv = (const float*)d_in[2];
  const float* Wc   = (const float*)d_in[3];
  const float* bc   = (const float*)d_in[4];
  const float* Wr   = (const float*)d_in[5];
  const float* br   = (const float*)d_in[6];
  const float* Wd   = (const float*)d_in[7];
  const float* bd   = (const float*)d_in[8];
  float* out = (float*)d_out;

  char* ws = (char*)d_ws;
  u16* QKV   = (u16*)(ws);                  // 48 MB  [1-5] (V third unused)
  u16* Xb    = (u16*)(ws + 50331648);       // 16 MB  [cvt-..]
  u16* AO    = (u16*)(ws + 50331648);       //        [attn-5]
  u16* Wqkvb = (u16*)(ws + 67108864);       // 24 MB  [cvt-1]
  u16* VrT   = (u16*)(ws + 67108864);       // 16 MB  [3-4] (aliases Wqkvb)
  u16* Wcb   = (u16*)(ws + 92274688);       // 1.25 MB
  u16* Wrb   = (u16*)(ws + 93585408);       // 1.25 MB
  u16* Cb    = (u16*)(ws + 94896128);       // 2.5 MB
  u16* Wdb   = (u16*)(ws + 97517568);       // 8 MB
  u16* WvTb  = (u16*)(ws + 105906176);      // 8 MB   Wv^T bf16
  u16* Wvc   = (u16*)(ws + 114294784);      // 1.5 MB (384x2048, rows 320+ junk)
  float* bc2 = (float*)(ws + 115867648);    // 1.25 KB

  dim3 blk(256);

  // 0. convert f32 inputs -> bf16
  cvt_kernel<<<dim3(512, 5), blk, 0, stream>>>(
      X, Xb, 4096 * 2048,
      Wqkv, Wqkvb, 6144 * 2048,
      Wc, Wcb, 320 * 2048,
      Wr, Wrb, 2048 * 320,
      Wd, Wdb, 2048 * 2048);

  // 0b. WvT = Wv^T (bf16), from f32 Wqkv rows 4096..6143
  transpose_wv_kernel<<<dim3(32, 32), blk, 0, stream>>>(Wqkv, WvTb);
  // 0c. bc2 = bc + Wc @ bv
  bc2_kernel<<<dim3(80), blk, 0, stream>>>(Wcb, bqkv, bc, bc2);
  // 0d. Wvc = Wc @ Wv  (= Wc @ WvT^T), no bias. Rows 320..383 of A are junk
  //     reads into Wrb (in-bounds); output rows 320..383 junk, never used.
  gemm_bias_kernel<0, 0, 0, 1><<<dim3(16, 3), blk, 0, stream>>>(
      Wcb, WvTb, bc, Wvc, 320, 2048, 2048, 2048, 2048, 2048, 0, 0);

  // 1. QK projection with fused RoPE — N=4096, 256 blocks = one exact round
  gemm256_rope_kernel<<<dim3(16, 16), dim3(512), 0, stream>>>(
      Xb, Wqkvb, bqkv, QKV, 4096, 4096, 2048, 2048, 2048, 6144);
  // 2. Cb = X @ Wvc^T + bc2   (V projection folded: == V_hidden @ Wc^T + bc)
  gemm_bias_kernel<0, 0, 0, 0><<<dim3(3, 32), blk, 0, stream>>>(
      Xb, Wvc, bc2, Cb, 4096, 320, 2048, 2048, 2048, 320, 0, 0);
  // 3. VrT = (Cb @ Wr^T)^T + br  == Wr @ Cb^T, per batch (z=2)
  gemm_bias_kernel<0, 0, 1, 0><<<dim3(16, 16, 2), blk, 0, stream>>>(
      Wrb, Cb, br, VrT, 2048, 2048, 320, 320, 320, 2048,
      (size_t)2048 * 320, (size_t)4194304);
  // 4. MFMA causal flash attention -> AO (bf16, hidden layout), paired q-tiles
  attn_mfma_kernel<<<dim3(512), blk, 0, stream>>>(QKV, VrT, AO);
  // 5. output projection -> f32 d_out
  gemm_bias_kernel<1, 0, 0, 0><<<dim3(16, 32), blk, 0, stream>>>(
      AO, Wdb, bd, out, 4096, 2048, 2048, 2048, 2048, 2048, 0, 0);
}